// Round 4
// baseline (233.368 us; speedup 1.0000x reference)
//
#include <hip/hip_runtime.h>

#define NUM_FACES 400000
#define NVIEW 4
#define NCHAN 64
#define IMGS 512

// ---------------------------------------------------------------------------
// Kernel 1: scatter pix_to_face into a per-view visibility byte table.
// ---------------------------------------------------------------------------
__global__ void scatter_vis_kernel(const int* __restrict__ p2f,
                                   unsigned char* __restrict__ table,
                                   int total) {
    int i = blockIdx.x * blockDim.x + threadIdx.x;
    if (i >= total) return;
    int v = i / (IMGS * IMGS);
    int f = p2f[i];
    if (f >= 0) table[(size_t)v * NUM_FACES + f] = 1;
}

// ---------------------------------------------------------------------------
// Kernel 1b: transpose feature [V,C,S,S] -> [V,S,S,C] so that the sampler's
// per-pixel 64-channel read is 256 B contiguous (1 coalesced wave read).
// Tile: 64 channels x 64 x-positions for one (v,y). LDS stride 65 -> no
// bank conflicts on either phase.
// ---------------------------------------------------------------------------
__global__ __launch_bounds__(256) void transpose_feat_kernel(
    const float* __restrict__ feature,  // [V,C,S,S]
    float* __restrict__ feat_t)         // [V,S,S,C]
{
    __shared__ float tile[64 * 65];
    int b = blockIdx.x;
    int xt = b % (IMGS / 64);
    int y  = (b / (IMGS / 64)) % IMGS;
    int v  = b / ((IMGS / 64) * IMGS);
    int x0 = xt * 64;
    const size_t SS = (size_t)IMGS * IMGS;

    const float* src = feature + (size_t)v * NCHAN * SS + (size_t)y * IMGS + x0;
#pragma unroll
    for (int i = 0; i < 16; ++i) {
        int lin = i * 256 + threadIdx.x;
        int c = lin >> 6;   // wave-uniform
        int x = lin & 63;   // lane -> contiguous global read
        tile[c * 65 + x] = src[(size_t)c * SS + x];
    }
    __syncthreads();

    float* dst = feat_t + (((size_t)v * IMGS + y) * IMGS + x0) * NCHAN;
#pragma unroll
    for (int i = 0; i < 16; ++i) {
        int lin = i * 256 + threadIdx.x;
        int x = lin >> 6;   // wave-uniform
        int c = lin & 63;   // lane -> contiguous global write
        dst[(size_t)x * NCHAN + c] = tile[c * 65 + x];
    }
}

// ---------------------------------------------------------------------------
// Kernel 2: project + mask + bilinear sample + weighted mean.
// Block = 256 = 4 vertices x 64 channels; one wave per vertex so the per-view
// mask skip is wave-uniform. TRANSPOSED=1 reads feat_t [V,S,S,C].
// ---------------------------------------------------------------------------
template <int TRANSPOSED>
__global__ __launch_bounds__(256) void project_sample_kernel(
    const float* __restrict__ verts,
    const int* __restrict__ faces,
    const float* __restrict__ cam_rot,   // [V,3,3]
    const float* __restrict__ cam_trans, // [V,3]
    const float* __restrict__ Kmat,      // [V,3,3]
    const float* __restrict__ feature,   // [V,C,S,S] or [V,S,S,C]
    const unsigned char* __restrict__ table, // [V,NUM_FACES]
    float* __restrict__ out,             // [N,C]
    int n_verts)
{
    int n = blockIdx.x * 4 + (threadIdx.x >> 6);
    int c = threadIdx.x & 63;
    if (n >= n_verts) return;

    float px = verts[n * 3 + 0];
    float py = verts[n * 3 + 1];
    float pz = verts[n * 3 + 2];
    int f = faces[n];

    float xs[NVIEW], ys[NVIEW], mask[NVIEW];
    float vsum = 0.f;

#pragma unroll
    for (int v = 0; v < NVIEW; ++v) {
        const float* R  = cam_rot   + v * 9;
        const float* t  = cam_trans + v * 3;
        const float* Km = Kmat      + v * 9;
        float cx = R[0] * px + R[1] * py + R[2] * pz + t[0];
        float cy = R[3] * px + R[4] * py + R[5] * pz + t[1];
        float cz = R[6] * px + R[7] * py + R[8] * pz + t[2];
        float qx = Km[0] * cx + Km[1] * cy + Km[2] * cz;
        float qy = Km[3] * cx + Km[4] * cy + Km[5] * cz;
        float qz = Km[6] * cx + Km[7] * cy + Km[8] * cz;
        xs[v] = qx / qz;
        ys[v] = qy / qz;
        float m = (f >= 0 && table[(size_t)v * NUM_FACES + f]) ? 1.f : 0.f;
        mask[v] = m;
        vsum += m;
    }

    float wsum = vsum;
    if (vsum == 0.f) {
#pragma unroll
        for (int v = 0; v < NVIEW; ++v) mask[v] = 1.f;
        wsum = (float)NVIEW;
    }

    float acc = 0.f;
#pragma unroll
    for (int v = 0; v < NVIEW; ++v) {
        if (mask[v] == 0.f) continue;  // wave-uniform skip
        float x = xs[v], y = ys[v];
        float x0f = floorf(x), y0f = floorf(y);
        float wx1 = x - x0f, wx0 = 1.f - wx1;
        float wy1 = y - y0f, wy0 = 1.f - wy1;
        int x0 = (int)x0f, y0 = (int)y0f;
        int x1 = x0 + 1, y1 = y0 + 1;
        bool vx0 = (x0 >= 0) && (x0 <= IMGS - 1);
        bool vx1 = (x1 >= 0) && (x1 <= IMGS - 1);
        bool vy0 = (y0 >= 0) && (y0 <= IMGS - 1);
        bool vy1 = (y1 >= 0) && (y1 <= IMGS - 1);
        int cx0 = min(max(x0, 0), IMGS - 1);
        int cx1 = min(max(x1, 0), IMGS - 1);
        int cy0 = min(max(y0, 0), IMGS - 1);
        int cy1 = min(max(y1, 0), IMGS - 1);

        float w00 = wx0 * wy0 * (float)(vx0 && vy0);
        float w10 = wx1 * wy0 * (float)(vx1 && vy0);
        float w01 = wx0 * wy1 * (float)(vx0 && vy1);
        float w11 = wx1 * wy1 * (float)(vx1 && vy1);

        float s;
        if (TRANSPOSED) {
            const float* fv = feature + (size_t)v * IMGS * IMGS * NCHAN;
            const float* p00 = fv + ((size_t)cy0 * IMGS + cx0) * NCHAN;
            const float* p10 = fv + ((size_t)cy0 * IMGS + cx1) * NCHAN;
            const float* p01 = fv + ((size_t)cy1 * IMGS + cx0) * NCHAN;
            const float* p11 = fv + ((size_t)cy1 * IMGS + cx1) * NCHAN;
            s = p00[c] * w00 + p10[c] * w10 + p01[c] * w01 + p11[c] * w11;
        } else {
            const float* fc = feature + ((size_t)v * NCHAN + c) * (size_t)(IMGS * IMGS);
            s = fc[cy0 * IMGS + cx0] * w00 + fc[cy0 * IMGS + cx1] * w10
              + fc[cy1 * IMGS + cx0] * w01 + fc[cy1 * IMGS + cx1] * w11;
        }
        acc += s;
    }

    out[(size_t)n * NCHAN + c] = acc / wsum;
}

extern "C" void kernel_launch(void* const* d_in, const int* in_sizes, int n_in,
                              void* d_out, int out_size, void* d_ws, size_t ws_size,
                              hipStream_t stream) {
    const float* verts     = (const float*)d_in[0];
    const int*   faces     = (const int*)d_in[1];
    const float* cam_rot   = (const float*)d_in[2];
    const float* cam_trans = (const float*)d_in[3];
    const float* Kmat      = (const float*)d_in[4];
    const float* feature   = (const float*)d_in[6];
    const int*   p2f       = (const int*)d_in[7];
    float* out = (float*)d_out;

    int n_verts = in_sizes[1];

    unsigned char* table = (unsigned char*)d_ws;
    size_t table_bytes = (size_t)NVIEW * NUM_FACES;
    size_t feat_off = (table_bytes + 255) & ~(size_t)255;
    size_t feat_bytes = (size_t)NVIEW * IMGS * IMGS * NCHAN * sizeof(float);
    bool use_transpose = (ws_size >= feat_off + feat_bytes);

    hipMemsetAsync(table, 0, table_bytes, stream);

    int total_pix = NVIEW * IMGS * IMGS;
    scatter_vis_kernel<<<(total_pix + 255) / 256, 256, 0, stream>>>(p2f, table, total_pix);

    int nblocks = (n_verts + 3) / 4;
    if (use_transpose) {
        float* feat_t = (float*)((char*)d_ws + feat_off);
        int tblocks = NVIEW * IMGS * (IMGS / 64);
        transpose_feat_kernel<<<tblocks, 256, 0, stream>>>(feature, feat_t);
        project_sample_kernel<1><<<nblocks, 256, 0, stream>>>(
            verts, faces, cam_rot, cam_trans, Kmat, feat_t, table, out, n_verts);
    } else {
        project_sample_kernel<0><<<nblocks, 256, 0, stream>>>(
            verts, faces, cam_rot, cam_trans, Kmat, feature, table, out, n_verts);
    }
}

// Round 5
// 203.552 us; speedup vs baseline: 1.1465x; 1.1465x over previous
//
#include <hip/hip_runtime.h>

#define NUM_FACES 400000
#define NVIEW 4
#define NCHAN 64
#define IMGS 512
#define XTILES (IMGS / 64)

__device__ __forceinline__ float bf2f(unsigned short u) {
    union { unsigned int i; float f; } x; x.i = ((unsigned int)u) << 16; return x.f;
}
__device__ __forceinline__ unsigned short f2bf(float f) {
    unsigned int u = __float_as_uint(f);
    return (unsigned short)((u + 0x7FFFu + ((u >> 16) & 1u)) >> 16);  // RNE
}

__device__ __forceinline__ void project_view(
    const float* __restrict__ cam_rot, const float* __restrict__ cam_trans,
    const float* __restrict__ Kmat, int v, float px, float py, float pz,
    float& x, float& y)
{
    const float* R  = cam_rot   + v * 9;
    const float* t  = cam_trans + v * 3;
    const float* Km = Kmat      + v * 9;
    float cx = R[0] * px + R[1] * py + R[2] * pz + t[0];
    float cy = R[3] * px + R[4] * py + R[5] * pz + t[1];
    float cz = R[6] * px + R[7] * py + R[8] * pz + t[2];
    float qx = Km[0] * cx + Km[1] * cy + Km[2] * cz;
    float qy = Km[3] * cx + Km[4] * cy + Km[5] * cz;
    float qz = Km[6] * cx + Km[7] * cy + Km[8] * cz;
    x = qx / qz;
    y = qy / qz;
}

// ---------------------------------------------------------------------------
// Kernel 0: scatter pix_to_face into per-view visibility byte table.
// ---------------------------------------------------------------------------
__global__ void scatter_vis_kernel(const int* __restrict__ p2f,
                                   unsigned char* __restrict__ table,
                                   int total) {
    int i = blockIdx.x * blockDim.x + threadIdx.x;
    if (i >= total) return;
    int v = i / (IMGS * IMGS);
    int f = p2f[i];
    if (f >= 0) table[(size_t)v * NUM_FACES + f] = 1;
}

// ---------------------------------------------------------------------------
// Kernel 0b: mark touched (v, y, x-tile) flags. Marks the clamped corner
// addresses for EVERY vertex x EVERY view (covers the all-invisible
// fallback, which samples all views). Racy same-value byte stores are fine.
// ---------------------------------------------------------------------------
__global__ void mark_tiles_kernel(const float* __restrict__ verts,
                                  const float* __restrict__ cam_rot,
                                  const float* __restrict__ cam_trans,
                                  const float* __restrict__ Kmat,
                                  unsigned char* __restrict__ flags, // [V,S,XTILES]
                                  int n_verts) {
    int i = blockIdx.x * blockDim.x + threadIdx.x;
    int n = i >> 2;
    int v = i & 3;
    if (n >= n_verts) return;
    float px = verts[n * 3 + 0], py = verts[n * 3 + 1], pz = verts[n * 3 + 2];
    float x, y;
    project_view(cam_rot, cam_trans, Kmat, v, px, py, pz, x, y);
    int x0 = (int)floorf(x), y0 = (int)floorf(y);
    int cx0 = min(max(x0, 0), IMGS - 1);
    int cx1 = min(max(x0 + 1, 0), IMGS - 1);
    int cy0 = min(max(y0, 0), IMGS - 1);
    int cy1 = min(max(y0 + 1, 0), IMGS - 1);
    unsigned char* fv = flags + (size_t)v * IMGS * XTILES;
    int t00 = cy0 * XTILES + (cx0 >> 6);
    int t10 = cy0 * XTILES + (cx1 >> 6);
    int t01 = cy1 * XTILES + (cx0 >> 6);
    int t11 = cy1 * XTILES + (cx1 >> 6);
    fv[t00] = 1;
    if (t10 != t00) fv[t10] = 1;
    fv[t01] = 1;
    if (t11 != t01) fv[t11] = 1;
}

// ---------------------------------------------------------------------------
// Kernel 1: transpose feature [V,C,S,S] f32 -> [V,S,S,C] bf16, skipping
// tiles no sampler address touches. Tile = 64 channels x 64 x for one (v,y).
// ---------------------------------------------------------------------------
__global__ __launch_bounds__(256) void transpose_feat_kernel(
    const float* __restrict__ feature,          // [V,C,S,S]
    unsigned short* __restrict__ feat_t,        // [V,S,S,C] bf16
    const unsigned char* __restrict__ flags)    // [V,S,XTILES]
{
    int b = blockIdx.x;
    int xt = b % XTILES;
    int y  = (b / XTILES) % IMGS;
    int v  = b / (XTILES * IMGS);
    if (!flags[((size_t)v * IMGS + y) * XTILES + xt]) return;

    __shared__ float tile[64 * 65];
    int x0 = xt * 64;
    const size_t SS = (size_t)IMGS * IMGS;

    const float* src = feature + (size_t)v * NCHAN * SS + (size_t)y * IMGS + x0;
#pragma unroll
    for (int i = 0; i < 16; ++i) {
        int lin = i * 256 + threadIdx.x;
        int c = lin >> 6;   // wave-uniform
        int x = lin & 63;   // lane -> contiguous global read
        tile[c * 65 + x] = src[(size_t)c * SS + x];
    }
    __syncthreads();

    unsigned short* dst = feat_t + (((size_t)v * IMGS + y) * IMGS + x0) * NCHAN;
#pragma unroll
    for (int i = 0; i < 8; ++i) {
        int lin = i * 256 + threadIdx.x;
        int x  = lin >> 5;   // 32-lane-uniform
        int cp = lin & 31;   // channel pair
        float a = tile[(2 * cp) * 65 + x];
        float b2 = tile[(2 * cp + 1) * 65 + x];
        ushort2 w; w.x = f2bf(a); w.y = f2bf(b2);
        *reinterpret_cast<ushort2*>(dst + (size_t)x * NCHAN + 2 * cp) = w;
    }
}

// ---------------------------------------------------------------------------
// Kernel 2: project + mask + bilinear sample (bf16 feat_t) + weighted mean.
// Block = 256 = 4 vertices x 64 channels; one wave per vertex so the
// per-view skip is wave-uniform.
// ---------------------------------------------------------------------------
__global__ __launch_bounds__(256) void project_sample_bf16_kernel(
    const float* __restrict__ verts,
    const int* __restrict__ faces,
    const float* __restrict__ cam_rot,
    const float* __restrict__ cam_trans,
    const float* __restrict__ Kmat,
    const unsigned short* __restrict__ feat_t,   // [V,S,S,C] bf16
    const unsigned char* __restrict__ table,     // [V,NUM_FACES]
    float* __restrict__ out,                     // [N,C]
    int n_verts)
{
    int n = blockIdx.x * 4 + (threadIdx.x >> 6);
    int c = threadIdx.x & 63;
    if (n >= n_verts) return;

    float px = verts[n * 3 + 0];
    float py = verts[n * 3 + 1];
    float pz = verts[n * 3 + 2];
    int f = faces[n];

    float xs[NVIEW], ys[NVIEW], mask[NVIEW];
    float vsum = 0.f;

#pragma unroll
    for (int v = 0; v < NVIEW; ++v) {
        project_view(cam_rot, cam_trans, Kmat, v, px, py, pz, xs[v], ys[v]);
        float m = (f >= 0 && table[(size_t)v * NUM_FACES + f]) ? 1.f : 0.f;
        mask[v] = m;
        vsum += m;
    }

    float wsum = vsum;
    if (vsum == 0.f) {
#pragma unroll
        for (int v = 0; v < NVIEW; ++v) mask[v] = 1.f;
        wsum = (float)NVIEW;
    }

    float acc = 0.f;
#pragma unroll
    for (int v = 0; v < NVIEW; ++v) {
        if (mask[v] == 0.f) continue;  // wave-uniform skip
        float x = xs[v], y = ys[v];
        float x0f = floorf(x), y0f = floorf(y);
        float wx1 = x - x0f, wx0 = 1.f - wx1;
        float wy1 = y - y0f, wy0 = 1.f - wy1;
        int x0 = (int)x0f, y0 = (int)y0f;
        int x1 = x0 + 1, y1 = y0 + 1;
        bool vx0 = (x0 >= 0) && (x0 <= IMGS - 1);
        bool vx1 = (x1 >= 0) && (x1 <= IMGS - 1);
        bool vy0 = (y0 >= 0) && (y0 <= IMGS - 1);
        bool vy1 = (y1 >= 0) && (y1 <= IMGS - 1);
        int cx0 = min(max(x0, 0), IMGS - 1);
        int cx1 = min(max(x1, 0), IMGS - 1);
        int cy0 = min(max(y0, 0), IMGS - 1);
        int cy1 = min(max(y1, 0), IMGS - 1);

        float w00 = wx0 * wy0 * (float)(vx0 && vy0);
        float w10 = wx1 * wy0 * (float)(vx1 && vy0);
        float w01 = wx0 * wy1 * (float)(vx0 && vy1);
        float w11 = wx1 * wy1 * (float)(vx1 && vy1);

        const unsigned short* fv = feat_t + (size_t)v * IMGS * IMGS * NCHAN;
        const unsigned short* p00 = fv + ((size_t)cy0 * IMGS + cx0) * NCHAN;
        const unsigned short* p10 = fv + ((size_t)cy0 * IMGS + cx1) * NCHAN;
        const unsigned short* p01 = fv + ((size_t)cy1 * IMGS + cx0) * NCHAN;
        const unsigned short* p11 = fv + ((size_t)cy1 * IMGS + cx1) * NCHAN;
        acc += bf2f(p00[c]) * w00 + bf2f(p10[c]) * w10
             + bf2f(p01[c]) * w01 + bf2f(p11[c]) * w11;
    }

    out[(size_t)n * NCHAN + c] = acc / wsum;
}

// ---------------------------------------------------------------------------
// Fallback (small ws): direct f32 gather from [V,C,S,S].
// ---------------------------------------------------------------------------
__global__ __launch_bounds__(256) void project_sample_direct_kernel(
    const float* __restrict__ verts,
    const int* __restrict__ faces,
    const float* __restrict__ cam_rot,
    const float* __restrict__ cam_trans,
    const float* __restrict__ Kmat,
    const float* __restrict__ feature,           // [V,C,S,S]
    const unsigned char* __restrict__ table,
    float* __restrict__ out,
    int n_verts)
{
    int n = blockIdx.x * 4 + (threadIdx.x >> 6);
    int c = threadIdx.x & 63;
    if (n >= n_verts) return;

    float px = verts[n * 3 + 0], py = verts[n * 3 + 1], pz = verts[n * 3 + 2];
    int f = faces[n];
    float xs[NVIEW], ys[NVIEW], mask[NVIEW];
    float vsum = 0.f;
#pragma unroll
    for (int v = 0; v < NVIEW; ++v) {
        project_view(cam_rot, cam_trans, Kmat, v, px, py, pz, xs[v], ys[v]);
        float m = (f >= 0 && table[(size_t)v * NUM_FACES + f]) ? 1.f : 0.f;
        mask[v] = m; vsum += m;
    }
    float wsum = vsum;
    if (vsum == 0.f) {
#pragma unroll
        for (int v = 0; v < NVIEW; ++v) mask[v] = 1.f;
        wsum = (float)NVIEW;
    }
    float acc = 0.f;
#pragma unroll
    for (int v = 0; v < NVIEW; ++v) {
        if (mask[v] == 0.f) continue;
        float x = xs[v], y = ys[v];
        float x0f = floorf(x), y0f = floorf(y);
        float wx1 = x - x0f, wx0 = 1.f - wx1;
        float wy1 = y - y0f, wy0 = 1.f - wy1;
        int x0 = (int)x0f, y0 = (int)y0f;
        int x1 = x0 + 1, y1 = y0 + 1;
        bool vx0 = (x0 >= 0) && (x0 <= IMGS - 1), vx1 = (x1 >= 0) && (x1 <= IMGS - 1);
        bool vy0 = (y0 >= 0) && (y0 <= IMGS - 1), vy1 = (y1 >= 0) && (y1 <= IMGS - 1);
        int cx0 = min(max(x0, 0), IMGS - 1), cx1 = min(max(x1, 0), IMGS - 1);
        int cy0 = min(max(y0, 0), IMGS - 1), cy1 = min(max(y1, 0), IMGS - 1);
        const float* fc = feature + ((size_t)v * NCHAN + c) * (size_t)(IMGS * IMGS);
        acc += fc[cy0 * IMGS + cx0] * (wx0 * wy0 * (float)(vx0 && vy0))
             + fc[cy0 * IMGS + cx1] * (wx1 * wy0 * (float)(vx1 && vy0))
             + fc[cy1 * IMGS + cx0] * (wx0 * wy1 * (float)(vx0 && vy1))
             + fc[cy1 * IMGS + cx1] * (wx1 * wy1 * (float)(vx1 && vy1));
    }
    out[(size_t)n * NCHAN + c] = acc / wsum;
}

extern "C" void kernel_launch(void* const* d_in, const int* in_sizes, int n_in,
                              void* d_out, int out_size, void* d_ws, size_t ws_size,
                              hipStream_t stream) {
    const float* verts     = (const float*)d_in[0];
    const int*   faces     = (const int*)d_in[1];
    const float* cam_rot   = (const float*)d_in[2];
    const float* cam_trans = (const float*)d_in[3];
    const float* Kmat      = (const float*)d_in[4];
    const float* feature   = (const float*)d_in[6];
    const int*   p2f       = (const int*)d_in[7];
    float* out = (float*)d_out;

    int n_verts = in_sizes[1];

    // d_ws layout: [vis table][tile flags][align][feat_t bf16]
    unsigned char* table = (unsigned char*)d_ws;
    size_t table_bytes = (size_t)NVIEW * NUM_FACES;
    size_t flag_off   = table_bytes;
    size_t flag_bytes = (size_t)NVIEW * IMGS * XTILES;
    size_t feat_off   = (flag_off + flag_bytes + 255) & ~(size_t)255;
    size_t feat_bytes = (size_t)NVIEW * IMGS * IMGS * NCHAN * sizeof(unsigned short);
    bool use_transpose = (ws_size >= feat_off + feat_bytes);

    // zero vis table + tile flags in one memset (ws is poisoned 0xAA)
    hipMemsetAsync(table, 0, flag_off + flag_bytes, stream);

    int total_pix = NVIEW * IMGS * IMGS;
    scatter_vis_kernel<<<(total_pix + 255) / 256, 256, 0, stream>>>(p2f, table, total_pix);

    int nblocks = (n_verts + 3) / 4;
    if (use_transpose) {
        unsigned char* flags = (unsigned char*)d_ws + flag_off;
        unsigned short* feat_t = (unsigned short*)((char*)d_ws + feat_off);
        int mthreads = n_verts * NVIEW;
        mark_tiles_kernel<<<(mthreads + 255) / 256, 256, 0, stream>>>(
            verts, cam_rot, cam_trans, Kmat, flags, n_verts);
        int tblocks = NVIEW * IMGS * XTILES;
        transpose_feat_kernel<<<tblocks, 256, 0, stream>>>(feature, feat_t, flags);
        project_sample_bf16_kernel<<<nblocks, 256, 0, stream>>>(
            verts, faces, cam_rot, cam_trans, Kmat, feat_t, table, out, n_verts);
    } else {
        project_sample_direct_kernel<<<nblocks, 256, 0, stream>>>(
            verts, faces, cam_rot, cam_trans, Kmat, feature, table, out, n_verts);
    }
}

// Round 6
// 188.600 us; speedup vs baseline: 1.2374x; 1.0793x over previous
//
#include <hip/hip_runtime.h>

#define NUM_FACES 400000
#define NVIEW 4
#define NCHAN 64
#define IMGS 512
#define XTILES (IMGS / 64)

typedef float f32x4 __attribute__((ext_vector_type(4)));

__device__ __forceinline__ float bf2f(unsigned short u) {
    union { unsigned int i; float f; } x; x.i = ((unsigned int)u) << 16; return x.f;
}
__device__ __forceinline__ unsigned short f2bf(float f) {
    unsigned int u = __float_as_uint(f);
    return (unsigned short)((u + 0x7FFFu + ((u >> 16) & 1u)) >> 16);  // RNE
}

__device__ __forceinline__ void project_view(
    const float* __restrict__ cam_rot, const float* __restrict__ cam_trans,
    const float* __restrict__ Kmat, int v, float px, float py, float pz,
    float& x, float& y)
{
    const float* R  = cam_rot   + v * 9;
    const float* t  = cam_trans + v * 3;
    const float* Km = Kmat      + v * 9;
    float cx = R[0] * px + R[1] * py + R[2] * pz + t[0];
    float cy = R[3] * px + R[4] * py + R[5] * pz + t[1];
    float cz = R[6] * px + R[7] * py + R[8] * pz + t[2];
    float qx = Km[0] * cx + Km[1] * cy + Km[2] * cz;
    float qy = Km[3] * cx + Km[4] * cy + Km[5] * cz;
    float qz = Km[6] * cx + Km[7] * cy + Km[8] * cz;
    x = qx / qz;
    y = qy / qz;
}

// ---------------------------------------------------------------------------
// Kernel 0 (fused): range [0, total_pix) scatters pix_to_face into the
// per-view visibility table; range [total_pix, total_pix + N*V) projects
// every vertex x view and marks touched (v, y, x-tile) flags. total_pix is a
// multiple of 256, so the range split is block-aligned (no divergence).
// Racy same-value byte stores are fine.
// ---------------------------------------------------------------------------
__global__ void prep_kernel(const int* __restrict__ p2f,
                            unsigned char* __restrict__ table,   // [V,NUM_FACES]
                            const float* __restrict__ verts,
                            const float* __restrict__ cam_rot,
                            const float* __restrict__ cam_trans,
                            const float* __restrict__ Kmat,
                            unsigned char* __restrict__ flags,   // [V,S,XTILES]
                            int n_verts) {
    const int total_pix = NVIEW * IMGS * IMGS;
    int i = blockIdx.x * blockDim.x + threadIdx.x;
    if (i < total_pix) {
        int v = i / (IMGS * IMGS);
        int f = p2f[i];
        if (f >= 0) table[(size_t)v * NUM_FACES + f] = 1;
        return;
    }
    int j = i - total_pix;
    int n = j >> 2;
    int v = j & 3;
    if (n >= n_verts) return;
    float px = verts[n * 3 + 0], py = verts[n * 3 + 1], pz = verts[n * 3 + 2];
    float x, y;
    project_view(cam_rot, cam_trans, Kmat, v, px, py, pz, x, y);
    int x0 = (int)floorf(x), y0 = (int)floorf(y);
    int cx0 = min(max(x0, 0), IMGS - 1);
    int cx1 = min(max(x0 + 1, 0), IMGS - 1);
    int cy0 = min(max(y0, 0), IMGS - 1);
    int cy1 = min(max(y0 + 1, 0), IMGS - 1);
    unsigned char* fv = flags + (size_t)v * IMGS * XTILES;
    int t00 = cy0 * XTILES + (cx0 >> 6);
    int t10 = cy0 * XTILES + (cx1 >> 6);
    int t01 = cy1 * XTILES + (cx0 >> 6);
    int t11 = cy1 * XTILES + (cx1 >> 6);
    fv[t00] = 1;
    if (t10 != t00) fv[t10] = 1;
    fv[t01] = 1;
    if (t11 != t01) fv[t11] = 1;
}

// ---------------------------------------------------------------------------
// Kernel 1: transpose feature [V,C,S,S] f32 -> [V,S,S,C] bf16, skipping
// untouched tiles. Tile = 64 channels x 64 x for one (v,y).
// f32 reads are NONTEMPORAL (read-once stream) so they don't evict the
// freshly written feat_t from the 256 MB LLC — the sampler re-reads feat_t.
// LDS stride 65: both phases <=2-way bank aliasing (free).
// ---------------------------------------------------------------------------
__global__ __launch_bounds__(256) void transpose_feat_kernel(
    const float* __restrict__ feature,          // [V,C,S,S]
    unsigned short* __restrict__ feat_t,        // [V,S,S,C] bf16
    const unsigned char* __restrict__ flags)    // [V,S,XTILES]
{
    int b = blockIdx.x;
    int xt = b % XTILES;
    int y  = (b / XTILES) % IMGS;
    int v  = b / (XTILES * IMGS);
    if (!flags[((size_t)v * IMGS + y) * XTILES + xt]) return;

    __shared__ float tile[64 * 65];
    int x0 = xt * 64;
    const size_t SS = (size_t)IMGS * IMGS;

    const float* src = feature + (size_t)v * NCHAN * SS + (size_t)y * IMGS + x0;
#pragma unroll
    for (int i = 0; i < 4; ++i) {
        int lin = i * 256 + threadIdx.x;   // 0..1023
        int c  = lin >> 4;                 // channel
        int xq = (lin & 15) * 4;           // x quad (16B aligned)
        f32x4 val = __builtin_nontemporal_load(
            reinterpret_cast<const f32x4*>(src + (size_t)c * SS + xq));
        tile[c * 65 + xq + 0] = val.x;
        tile[c * 65 + xq + 1] = val.y;
        tile[c * 65 + xq + 2] = val.z;
        tile[c * 65 + xq + 3] = val.w;
    }
    __syncthreads();

    unsigned short* dst = feat_t + (((size_t)v * IMGS + y) * IMGS + x0) * NCHAN;
#pragma unroll
    for (int i = 0; i < 4; ++i) {
        int lin = i * 256 + threadIdx.x;
        int x  = lin >> 4;                 // x position
        int c0 = (lin & 15) * 4;           // channel quad
        ushort4 w;
        w.x = f2bf(tile[(c0 + 0) * 65 + x]);
        w.y = f2bf(tile[(c0 + 1) * 65 + x]);
        w.z = f2bf(tile[(c0 + 2) * 65 + x]);
        w.w = f2bf(tile[(c0 + 3) * 65 + x]);
        *reinterpret_cast<ushort4*>(dst + (size_t)x * NCHAN + c0) = w;
    }
}

// ---------------------------------------------------------------------------
// Kernel 2: project + mask + bilinear sample (bf16 feat_t) + weighted mean.
// Block = 256 = 4 vertices x 64 channels; one wave per vertex so the
// per-view skip is wave-uniform. out store is nontemporal (write-once).
// ---------------------------------------------------------------------------
__global__ __launch_bounds__(256) void project_sample_bf16_kernel(
    const float* __restrict__ verts,
    const int* __restrict__ faces,
    const float* __restrict__ cam_rot,
    const float* __restrict__ cam_trans,
    const float* __restrict__ Kmat,
    const unsigned short* __restrict__ feat_t,   // [V,S,S,C] bf16
    const unsigned char* __restrict__ table,     // [V,NUM_FACES]
    float* __restrict__ out,                     // [N,C]
    int n_verts)
{
    int n = blockIdx.x * 4 + (threadIdx.x >> 6);
    int c = threadIdx.x & 63;
    if (n >= n_verts) return;

    float px = verts[n * 3 + 0];
    float py = verts[n * 3 + 1];
    float pz = verts[n * 3 + 2];
    int f = faces[n];

    float xs[NVIEW], ys[NVIEW], mask[NVIEW];
    float vsum = 0.f;

#pragma unroll
    for (int v = 0; v < NVIEW; ++v) {
        project_view(cam_rot, cam_trans, Kmat, v, px, py, pz, xs[v], ys[v]);
        float m = (f >= 0 && table[(size_t)v * NUM_FACES + f]) ? 1.f : 0.f;
        mask[v] = m;
        vsum += m;
    }

    float wsum = vsum;
    if (vsum == 0.f) {
#pragma unroll
        for (int v = 0; v < NVIEW; ++v) mask[v] = 1.f;
        wsum = (float)NVIEW;
    }

    float acc = 0.f;
#pragma unroll
    for (int v = 0; v < NVIEW; ++v) {
        if (mask[v] == 0.f) continue;  // wave-uniform skip
        float x = xs[v], y = ys[v];
        float x0f = floorf(x), y0f = floorf(y);
        float wx1 = x - x0f, wx0 = 1.f - wx1;
        float wy1 = y - y0f, wy0 = 1.f - wy1;
        int x0 = (int)x0f, y0 = (int)y0f;
        int x1 = x0 + 1, y1 = y0 + 1;
        bool vx0 = (x0 >= 0) && (x0 <= IMGS - 1);
        bool vx1 = (x1 >= 0) && (x1 <= IMGS - 1);
        bool vy0 = (y0 >= 0) && (y0 <= IMGS - 1);
        bool vy1 = (y1 >= 0) && (y1 <= IMGS - 1);
        int cx0 = min(max(x0, 0), IMGS - 1);
        int cx1 = min(max(x1, 0), IMGS - 1);
        int cy0 = min(max(y0, 0), IMGS - 1);
        int cy1 = min(max(y1, 0), IMGS - 1);

        float w00 = wx0 * wy0 * (float)(vx0 && vy0);
        float w10 = wx1 * wy0 * (float)(vx1 && vy0);
        float w01 = wx0 * wy1 * (float)(vx0 && vy1);
        float w11 = wx1 * wy1 * (float)(vx1 && vy1);

        const unsigned short* fv = feat_t + (size_t)v * IMGS * IMGS * NCHAN;
        const unsigned short* p00 = fv + ((size_t)cy0 * IMGS + cx0) * NCHAN;
        const unsigned short* p10 = fv + ((size_t)cy0 * IMGS + cx1) * NCHAN;
        const unsigned short* p01 = fv + ((size_t)cy1 * IMGS + cx0) * NCHAN;
        const unsigned short* p11 = fv + ((size_t)cy1 * IMGS + cx1) * NCHAN;
        acc += bf2f(p00[c]) * w00 + bf2f(p10[c]) * w10
             + bf2f(p01[c]) * w01 + bf2f(p11[c]) * w11;
    }

    __builtin_nontemporal_store(acc / wsum, out + (size_t)n * NCHAN + c);
}

// ---------------------------------------------------------------------------
// Fallback (small ws): direct f32 gather from [V,C,S,S].
// ---------------------------------------------------------------------------
__global__ __launch_bounds__(256) void project_sample_direct_kernel(
    const float* __restrict__ verts,
    const int* __restrict__ faces,
    const float* __restrict__ cam_rot,
    const float* __restrict__ cam_trans,
    const float* __restrict__ Kmat,
    const float* __restrict__ feature,           // [V,C,S,S]
    const unsigned char* __restrict__ table,
    float* __restrict__ out,
    int n_verts)
{
    int n = blockIdx.x * 4 + (threadIdx.x >> 6);
    int c = threadIdx.x & 63;
    if (n >= n_verts) return;

    float px = verts[n * 3 + 0], py = verts[n * 3 + 1], pz = verts[n * 3 + 2];
    int f = faces[n];
    float xs[NVIEW], ys[NVIEW], mask[NVIEW];
    float vsum = 0.f;
#pragma unroll
    for (int v = 0; v < NVIEW; ++v) {
        project_view(cam_rot, cam_trans, Kmat, v, px, py, pz, xs[v], ys[v]);
        float m = (f >= 0 && table[(size_t)v * NUM_FACES + f]) ? 1.f : 0.f;
        mask[v] = m; vsum += m;
    }
    float wsum = vsum;
    if (vsum == 0.f) {
#pragma unroll
        for (int v = 0; v < NVIEW; ++v) mask[v] = 1.f;
        wsum = (float)NVIEW;
    }
    float acc = 0.f;
#pragma unroll
    for (int v = 0; v < NVIEW; ++v) {
        if (mask[v] == 0.f) continue;
        float x = xs[v], y = ys[v];
        float x0f = floorf(x), y0f = floorf(y);
        float wx1 = x - x0f, wx0 = 1.f - wx1;
        float wy1 = y - y0f, wy0 = 1.f - wy1;
        int x0 = (int)x0f, y0 = (int)y0f;
        int x1 = x0 + 1, y1 = y0 + 1;
        bool vx0 = (x0 >= 0) && (x0 <= IMGS - 1), vx1 = (x1 >= 0) && (x1 <= IMGS - 1);
        bool vy0 = (y0 >= 0) && (y0 <= IMGS - 1), vy1 = (y1 >= 0) && (y1 <= IMGS - 1);
        int cx0 = min(max(x0, 0), IMGS - 1), cx1 = min(max(x1, 0), IMGS - 1);
        int cy0 = min(max(y0, 0), IMGS - 1), cy1 = min(max(y1, 0), IMGS - 1);
        const float* fc = feature + ((size_t)v * NCHAN + c) * (size_t)(IMGS * IMGS);
        acc += fc[cy0 * IMGS + cx0] * (wx0 * wy0 * (float)(vx0 && vy0))
             + fc[cy0 * IMGS + cx1] * (wx1 * wy0 * (float)(vx1 && vy0))
             + fc[cy1 * IMGS + cx0] * (wx0 * wy1 * (float)(vx0 && vy1))
             + fc[cy1 * IMGS + cx1] * (wx1 * wy1 * (float)(vx1 && vy1));
    }
    out[(size_t)n * NCHAN + c] = acc / wsum;
}

extern "C" void kernel_launch(void* const* d_in, const int* in_sizes, int n_in,
                              void* d_out, int out_size, void* d_ws, size_t ws_size,
                              hipStream_t stream) {
    const float* verts     = (const float*)d_in[0];
    const int*   faces     = (const int*)d_in[1];
    const float* cam_rot   = (const float*)d_in[2];
    const float* cam_trans = (const float*)d_in[3];
    const float* Kmat      = (const float*)d_in[4];
    const float* feature   = (const float*)d_in[6];
    const int*   p2f       = (const int*)d_in[7];
    float* out = (float*)d_out;

    int n_verts = in_sizes[1];

    // d_ws layout: [vis table][tile flags][align][feat_t bf16]
    unsigned char* table = (unsigned char*)d_ws;
    size_t table_bytes = (size_t)NVIEW * NUM_FACES;
    size_t flag_off   = table_bytes;
    size_t flag_bytes = (size_t)NVIEW * IMGS * XTILES;
    size_t feat_off   = (flag_off + flag_bytes + 255) & ~(size_t)255;
    size_t feat_bytes = (size_t)NVIEW * IMGS * IMGS * NCHAN * sizeof(unsigned short);
    bool use_transpose = (ws_size >= feat_off + feat_bytes);

    // zero vis table + tile flags in one memset (ws is poisoned 0xAA)
    hipMemsetAsync(table, 0, flag_off + flag_bytes, stream);

    const int total_pix = NVIEW * IMGS * IMGS;  // multiple of 256
    int nblocks = (n_verts + 3) / 4;
    if (use_transpose) {
        unsigned char* flags = (unsigned char*)d_ws + flag_off;
        unsigned short* feat_t = (unsigned short*)((char*)d_ws + feat_off);
        int prep_total = total_pix + n_verts * NVIEW;
        prep_kernel<<<(prep_total + 255) / 256, 256, 0, stream>>>(
            p2f, table, verts, cam_rot, cam_trans, Kmat, flags, n_verts);
        int tblocks = NVIEW * IMGS * XTILES;
        transpose_feat_kernel<<<tblocks, 256, 0, stream>>>(feature, feat_t, flags);
        project_sample_bf16_kernel<<<nblocks, 256, 0, stream>>>(
            verts, faces, cam_rot, cam_trans, Kmat, feat_t, table, out, n_verts);
    } else {
        prep_kernel<<<(total_pix + 255) / 256, 256, 0, stream>>>(
            p2f, table, verts, cam_rot, cam_trans, Kmat,
            (unsigned char*)d_ws + flag_off, n_verts);
        project_sample_direct_kernel<<<nblocks, 256, 0, stream>>>(
            verts, faces, cam_rot, cam_trans, Kmat, feature, table, out, n_verts);
    }
}